// Round 1
// 108.590 us; speedup vs baseline: 1.1351x; 1.1351x over previous
//
#include <hip/hip_runtime.h>
#include <hip/hip_bf16.h>

#define N_PTS 65536
#define LOG2E 1.4426950408889634f

typedef __attribute__((ext_vector_type(8))) short short8;
typedef __attribute__((ext_vector_type(4))) short short4v;
typedef __attribute__((ext_vector_type(4))) float float4v;

#if __has_builtin(__builtin_amdgcn_exp2f)
#define EXP2F(x) __builtin_amdgcn_exp2f(x)
#else
#define EXP2F(x) exp2f(x)
#endif

__device__ __forceinline__ short f2b(float f) {
    __hip_bfloat16 h = __float2bfloat16(f);
    return *(short*)&h;
}
__device__ __forceinline__ float b2f(short s) {
    __hip_bfloat16 h = *(__hip_bfloat16*)&s;
    return __bfloat162float(h);
}

// ---------------- prep (unchanged layout/offsets) ----------------
//   zb   [1024][16] bf16  @ 0        bf16(log2e * z)
//   FbB  [8][64][16] bf16 @ 32768    FbB[o][l][i] = bf16(F[o][i][l])
//   BWd  [64][512] bf16   @ 49152    block-diag sqrt(2/64)*pw
//   Wtb  [64][1024] bf16  @ 114688   bf16(W)
//   z2h  [1024] f32       @ 245760   0.5*log2e*||bf16(z_m)||^2
__global__ __launch_bounds__(256) void prep_kernel(
    const float* __restrict__ z, const float* __restrict__ W,
    const float* __restrict__ F, const float* __restrict__ pw,
    short* __restrict__ zb, short* __restrict__ FbB,
    short* __restrict__ BWd, short* __restrict__ Wtb,
    float* __restrict__ z2h)
{
    int t = blockIdx.x * 256 + threadIdx.x;
    if (t < 16384) {
        zb[t] = f2b(LOG2E * z[t]);
    } else if (t < 17408) {
        int m = t - 16384;
        const float4v* zp = (const float4v*)(z + (size_t)m * 16);
        float s = 0.f;
        #pragma unroll
        for (int k = 0; k < 4; k++) {
            float4v v = zp[k];
            float a0 = b2f(f2b(v.x)), a1 = b2f(f2b(v.y));
            float a2 = b2f(f2b(v.z)), a3 = b2f(f2b(v.w));
            s += a0 * a0 + a1 * a1 + a2 * a2 + a3 * a3;
        }
        z2h[m] = 0.5f * LOG2E * s;
    } else if (t < 25600) {
        int p = t - 17408;
        int o = p >> 10, l = (p >> 4) & 63, i = p & 15;
        FbB[p] = f2b(F[o * 1024 + i * 64 + l]);
    } else if (t < 58368) {
        int p = t - 25600;
        int so = p >> 9, ol = p & 511, o = ol >> 6;
        float v = ((so & 7) == o) ? 0.17677669529663687f * pw[so * 64 + (ol & 63)] : 0.f;
        BWd[p] = f2b(v);
    } else if (t < 123904) {
        int p = t - 58368;
        Wtb[p] = f2b(W[p]);
    }
}

// ---------------- fused prior + data, barrier-free K-split ----------------
// 256 thr = 4 waves. Each wave owns a K-quarter (256 m / 128 l) for ALL
// 64 so x 64 n, accumulating into acc[4][4] (64 VGPR). Private 4KB LDS
// tile per wave; producer->consumer ordered by the in-order DS pipe, so
// there are NO barriers in the main loop. Epilogue: pairwise reduction of
// the 4 partials through LDS (3 barriers).
//
// Swapped arg-MFMA (mfma(z_frag, x_frag)): D rows = m (4q+r), cols = n (c)
// -> d[0..3] are contiguous in the [n][m] tile -> one b64 packed write.
// Tile: [64 n rows][32 m shorts] = 64B rows, XOR swizzle byte^=((row&3)<<4)
// on both sides: writes hit the 4-round bank minimum, reads stay b128-floor.
//
// x2 trick: data exponent is (dot - z2) only; acc is scaled once by
// exp2(-x2[n]) before the prior phase accumulates on top.
__global__ __launch_bounds__(256, 3) void fused_kernel(
    const float* __restrict__ x, const float* __restrict__ ph,
    const short* __restrict__ zb, const short* __restrict__ FbB,
    const short* __restrict__ BWd, const short* __restrict__ Wtb,
    const float* __restrict__ z2h, float* __restrict__ out)
{
    // main-phase layout:  tiles [4][64][32]s @0 (16384) | phc 512f @16384
    //                     nz2 1024f @18432 | x2c 64f @22528   (end 22784)
    // epilogue overlay:   rbufA [64][68]f @0 | rbufB [64][68]f @17408 (end 34816)
    __shared__ __align__(16) char smem[34816];
    short* tiles = (short*)smem;
    float* phc   = (float*)(smem + 16384);
    float* nz2   = (float*)(smem + 18432);
    float* x2c   = (float*)(smem + 22528);
    float* rbufA = (float*)smem;
    float* rbufB = (float*)(smem + 17408);

    const int tid = threadIdx.x;
    const int lane = tid & 63, w = tid >> 6;
    const int q = lane >> 4, c = lane & 15;
    const int n0 = blockIdx.x * 64;

    // stage tables
    for (int i = tid; i < 512; i += 256) phc[i] = ph[i];
    for (int i = tid; i < 1024; i += 256) nz2[i] = -z2h[i];
    if (tid < 64) {
        float s = 0.f;
        const float4v* xr = (const float4v*)(x + (size_t)(n0 + tid) * 16);
        #pragma unroll
        for (int k = 0; k < 4; k++) {
            float4v v = xr[k];
            float a0 = b2f(f2b(v.x)), a1 = b2f(f2b(v.y));
            float a2 = b2f(f2b(v.z)), a3 = b2f(f2b(v.w));
            s += a0 * a0 + a1 * a1 + a2 * a2 + a3 * a3;
        }
        x2c[tid] = 0.5f * LOG2E * s;
    }

    // x B-fragments for all 4 n-groups (K=16 real, quads 2,3 zero)
    short8 ax[4];
    #pragma unroll
    for (int nt = 0; nt < 4; nt++) {
        ax[nt] = (short8)0;
        if (q < 2) {
            const float4v* xp = (const float4v*)(x + (size_t)(n0 + nt * 16 + c) * 16 + q * 8);
            float4v v0 = xp[0], v1 = xp[1];
            ax[nt][0] = f2b(v0.x); ax[nt][1] = f2b(v0.y);
            ax[nt][2] = f2b(v0.z); ax[nt][3] = f2b(v0.w);
            ax[nt][4] = f2b(v1.x); ax[nt][5] = f2b(v1.y);
            ax[nt][6] = f2b(v1.z); ax[nt][7] = f2b(v1.w);
        }
    }

    float4v acc[4][4];
    #pragma unroll
    for (int a = 0; a < 4; a++)
        #pragma unroll
        for (int nt = 0; nt < 4; nt++) acc[a][nt] = (float4v)(0.f);

    __syncthreads();   // staging done — last barrier before epilogue

    char* myt = (char*)tiles + w * 4096;
    const int swz = (c & 3) << 4;
    const int wb0 = (c * 64 + q * 8) ^ swz;        // write base, m-half 0
    const int wb1 = (c * 64 + 32 + q * 8) ^ swz;   // write base, m-half 1
    const int rb0 = (c * 64 + q * 16) ^ swz;       // read base

    // ============ data: exp2(x.z*log2e - z2) @ W^T, wave-private 256 m ============
    const int mbase = w * 256;
    #pragma unroll 2
    for (int mb = 0; mb < 8; mb++) {
        const int m0 = mbase + mb * 32;
        #pragma unroll
        for (int mh = 0; mh < 2; mh++) {
            short8 bz = (short8)0;
            if (q < 2) bz = *(const short8*)(zb + (size_t)(m0 + mh * 16 + c) * 16 + q * 8);
            float4v c0 = *(const float4v*)(nz2 + m0 + mh * 16 + 4 * q);
            const int wb = mh ? wb1 : wb0;
            #pragma unroll
            for (int nt = 0; nt < 4; nt++) {
                float4v d = __builtin_amdgcn_mfma_f32_16x16x32_bf16(bz, ax[nt], c0, 0, 0, 0);
                short4v pk;
                pk[0] = f2b(EXP2F(d[0])); pk[1] = f2b(EXP2F(d[1]));
                pk[2] = f2b(EXP2F(d[2])); pk[3] = f2b(EXP2F(d[3]));
                *(short4v*)(myt + nt * 1024 + wb) = pk;
            }
        }
        short8 aw[4];
        #pragma unroll
        for (int a = 0; a < 4; a++)
            aw[a] = *(const short8*)(Wtb + (size_t)(a * 16 + c) * 1024 + m0 + q * 8);
        #pragma unroll
        for (int nt = 0; nt < 4; nt++) {
            short8 bb = *(const short8*)(myt + nt * 1024 + rb0);
            #pragma unroll
            for (int a = 0; a < 4; a++)
                acc[a][nt] = __builtin_amdgcn_mfma_f32_16x16x32_bf16(aw[a], bb, acc[a][nt], 0, 0, 0);
        }
    }

    // scale data part by exp2(-x2[n])
    #pragma unroll
    for (int nt = 0; nt < 4; nt++) {
        float sxv = EXP2F(-x2c[nt * 16 + c]);
        #pragma unroll
        for (int a = 0; a < 4; a++) acc[a][nt] *= sxv;
    }

    // ============ prior: cos(x.F + ph) @ blockdiag(pws), wave-private 128 l ============
    const int lbase = w * 128;
    #pragma unroll 2
    for (int lb = 0; lb < 4; lb++) {
        const int l0 = lbase + lb * 32;
        #pragma unroll
        for (int mh = 0; mh < 2; mh++) {
            short8 bf = (short8)0;
            if (q < 2) bf = *(const short8*)(FbB + (size_t)(l0 + mh * 16 + c) * 16 + q * 8);
            float4v c0 = *(const float4v*)(phc + l0 + mh * 16 + 4 * q);
            const int wb = mh ? wb1 : wb0;
            #pragma unroll
            for (int nt = 0; nt < 4; nt++) {
                float4v d = __builtin_amdgcn_mfma_f32_16x16x32_bf16(bf, ax[nt], c0, 0, 0, 0);
                short4v pk;
                pk[0] = f2b(__cosf(d[0])); pk[1] = f2b(__cosf(d[1]));
                pk[2] = f2b(__cosf(d[2])); pk[3] = f2b(__cosf(d[3]));
                *(short4v*)(myt + nt * 1024 + wb) = pk;
            }
        }
        short8 aw[4];
        #pragma unroll
        for (int a = 0; a < 4; a++)
            aw[a] = *(const short8*)(BWd + (size_t)(a * 16 + c) * 512 + l0 + q * 8);
        #pragma unroll
        for (int nt = 0; nt < 4; nt++) {
            short8 bb = *(const short8*)(myt + nt * 1024 + rb0);
            #pragma unroll
            for (int a = 0; a < 4; a++)
                acc[a][nt] = __builtin_amdgcn_mfma_f32_16x16x32_bf16(aw[a], bb, acc[a][nt], 0, 0, 0);
        }
    }

    // ============ epilogue: reduce 4 wave-partials, store ============
    __syncthreads();
    if (w & 1) {                       // w1 -> A, w3 -> B
        float* rb = (w == 1) ? rbufA : rbufB;
        #pragma unroll
        for (int a = 0; a < 4; a++)
            #pragma unroll
            for (int nt = 0; nt < 4; nt++)
                #pragma unroll
                for (int r = 0; r < 4; r++)
                    rb[(a * 16 + 4 * q + r) * 68 + nt * 16 + c] = acc[a][nt][r];
    }
    __syncthreads();
    if (!(w & 1)) {                    // w0 += into A, w2 += into B
        float* rb = (w == 0) ? rbufA : rbufB;
        #pragma unroll
        for (int a = 0; a < 4; a++)
            #pragma unroll
            for (int nt = 0; nt < 4; nt++)
                #pragma unroll
                for (int r = 0; r < 4; r++) {
                    int idx = (a * 16 + 4 * q + r) * 68 + nt * 16 + c;
                    rb[idx] += acc[a][nt][r];
                }
    }
    __syncthreads();
    #pragma unroll
    for (int k = 0; k < 16; k++) {     // out = A + B, row-coalesced
        int idx = k * 256 + tid;
        int row = idx >> 6, nn = idx & 63;
        out[(size_t)row * N_PTS + n0 + nn] = rbufA[row * 68 + nn] + rbufB[row * 68 + nn];
    }
}

extern "C" void kernel_launch(void* const* d_in, const int* in_sizes, int n_in,
                              void* d_out, int out_size, void* d_ws, size_t ws_size,
                              hipStream_t stream) {
    const float* x  = (const float*)d_in[0];   // [65536][16]
    const float* z  = (const float*)d_in[1];   // [1024][16]
    const float* W  = (const float*)d_in[2];   // [8][8][1024] = [64][1024]
    const float* F  = (const float*)d_in[3];   // [8][16][64]
    const float* ph = (const float*)d_in[4];   // [8][64]
    const float* pw = (const float*)d_in[5];   // [8][8][64] = [64][64]
    float* out = (float*)d_out;                // [64][65536]

    char* ws = (char*)d_ws;
    short* zb  = (short*)(ws);            // 32768 B
    short* FbB = (short*)(ws + 32768);    // 16384 B
    short* BWd = (short*)(ws + 49152);    // 65536 B
    short* Wtb = (short*)(ws + 114688);   // 131072 B
    float* z2h = (float*)(ws + 245760);   // 4096 B

    prep_kernel<<<484, 256, 0, stream>>>(z, W, F, pw, zb, FbB, BWd, Wtb, z2h);
    fused_kernel<<<1024, 256, 0, stream>>>(x, ph, zb, FbB, BWd, Wtb, z2h, out);
}